// Round 4
// baseline (32.657 us; speedup 1.0000x reference)
//
#include <hip/hip_runtime.h>
#include <math.h>

#define S_ 32
#define B_ 128
#define M_ 128
#define F_ 512
#define C_ 100
#define MH 64    // m per block (m-half)
#define PB 16    // s-samples (pairs) per block (s-half)
#define PS 20    // Psh row stride in floats (16 p + 4 pad, float4-aligned)

// Grid (2 mh, 2 sh, 128 b), 512 threads = 8 waves. ~74 KB LDS -> 2 blocks/CU.
// Wave roles: B: thread(cc,q) owns beta-row-slice. C: wave g -> p=2g,2g+1.
// D: wave (Q=g&3, ch=g>>2): p-quad Q, c-half ch. E: exchange + epilogue.
__global__ __launch_bounds__(512, 4) void k_main(
    const float* __restrict__ x, const int* __restrict__ y,
    const float* __restrict__ Z, const float* __restrict__ alpha0,
    const float* __restrict__ alpha, const float* __restrict__ beta0,
    const float* __restrict__ beta, float* __restrict__ out) {
  const int mh = blockIdx.x;   // 0,1
  const int sh = blockIdx.y;   // 0,1
  const int b  = blockIdx.z;   // 0..127
  const int tid = threadIdx.x;
  const int lane = tid & 63;
  const int g = tid >> 6;      // wave 0..7
  const int s0 = sh * PB;

  __shared__ __align__(16) float2 epen[C_ * MH];   // 51.2 KB (ep,en) packed
  __shared__ __align__(16) float zsh[PB * M_];     // 8 KB, float4-slot swizzled
  __shared__ __align__(16) float scratch[PB * M_]; // 8 KB: bsh (B/C), exch (E)
  __shared__ __align__(16) float Psh[C_ * PS];     // 8 KB softmax P, [c][p] pad
  __shared__ float Pyb[PB];
  __shared__ float esh_eta[MH];

  const int yb = y[b];

  // ---------------- Phase A: staging ----------------
  // Z rows (16 p, full m), swizzled float4 slots: (p,m) -> word
  // p*128 + q*32 + ((i4^q)<<2) + j   with q=m>>5, i4=(m>>2)&7, j=m&3
#pragma unroll
  for (int k = 0; k < 4; ++k) {
    int i = tid + k * 512;  // 0..2047
    int p = i >> 7, m = i & 127;
    int qq = m >> 5, i4 = (m >> 2) & 7, jj = m & 3;
    zsh[p * 128 + qq * 32 + ((i4 ^ qq) << 2) + jj] =
        Z[((size_t)(s0 + p) * B_ + b) * M_ + m];
  }
  // epen for this m-half (computed in-block, no global table)
  for (int i = tid; i < C_ * MH; i += 512) {
    int c = i >> 6, mm = i & 63;
    float bv = beta[c * M_ + mh * MH + mm];
    epen[i] = make_float2(expf(2.f * bv), expf(-2.f * bv));
  }
  // beta row-slice into registers: thread (cc=tid>>2, q=tid&3) owns
  // beta[cc][q*32..q*32+31] as 8 float4
  const int cc = tid >> 2, q = tid & 3;
  float4 br[8];
  float b0r = 0.f;
  if (cc < C_) {
    const float4* beta4 = (const float4*)beta;
#pragma unroll
    for (int i4 = 0; i4 < 8; ++i4) br[i4] = beta4[cc * 32 + q * 8 + i4];
    b0r = beta0[cc];
  } else {
#pragma unroll
    for (int i4 = 0; i4 < 8; ++i4) br[i4] = make_float4(0.f, 0.f, 0.f, 0.f);
  }
  // eta (64 m of this mh): coalesced lanes-over-f wave-GEMV
  {
    const float4* x4 = (const float4*)x;
    float4 xa = x4[b * 128 + lane];
    float4 xb = x4[b * 128 + 64 + lane];
    const float4* a4 = (const float4*)alpha;
#pragma unroll
    for (int j = 0; j < 8; ++j) {
      int m = mh * MH + g * 8 + j;
      float4 a1 = a4[(size_t)m * 128 + lane];
      float4 a2 = a4[(size_t)m * 128 + 64 + lane];
      float acc = 0.f;
      acc = fmaf(a1.x, xa.x, acc); acc = fmaf(a1.y, xa.y, acc);
      acc = fmaf(a1.z, xa.z, acc); acc = fmaf(a1.w, xa.w, acc);
      acc = fmaf(a2.x, xb.x, acc); acc = fmaf(a2.y, xb.y, acc);
      acc = fmaf(a2.z, xb.z, acc); acc = fmaf(a2.w, xb.w, acc);
#pragma unroll
      for (int off = 32; off > 0; off >>= 1) acc += __shfl_xor(acc, off);
      if (lane == 0) {
        float l = alpha0[m] + acc;
        esh_eta[g * 8 + j] = 1.f / (1.f + expf(-l));
      }
    }
  }
  __syncthreads();  // (1) zsh, epen, esh_eta ready

  // ---------------- Phase B: base[p][c] -> scratch ----------------
  {
    const float4* zsh4 = (const float4*)zsh;
#pragma unroll 4
    for (int p = 0; p < PB; ++p) {
      float a0 = 0.f, a1 = 0.f, a2 = 0.f, a3 = 0.f;  // 4 chains
#pragma unroll
      for (int i4 = 0; i4 < 8; ++i4) {
        float4 zv = zsh4[p * 32 + q * 8 + (i4 ^ q)];
        float4 bb = br[i4];
        a0 = fmaf(bb.x, zv.x, a0);
        a1 = fmaf(bb.y, zv.y, a1);
        a2 = fmaf(bb.z, zv.z, a2);
        a3 = fmaf(bb.w, zv.w, a3);
      }
      float acc = (a0 + a1) + (a2 + a3);
      float r = acc + __shfl_xor(acc, 1);
      r = r + __shfl_xor(r, 2);
      if (q == 0 && cc < C_) scratch[p * 128 + cc] = r + b0r;
    }
  }
  __syncthreads();  // (2) base ready

  // ---------------- Phase C: softmax; wave g -> p = 2g, 2g+1 ----------------
  {
    int c0 = lane;
#pragma unroll
    for (int k = 0; k < 2; ++k) {
      int p = g * 2 + k;
      float v1 = scratch[p * 128 + c0];
      bool has2 = (c0 + 64) < C_;
      float v2 = has2 ? scratch[p * 128 + c0 + 64] : -INFINITY;
      float mx = fmaxf(v1, v2);
#pragma unroll
      for (int off = 32; off > 0; off >>= 1) mx = fmaxf(mx, __shfl_xor(mx, off));
      float e1 = expf(v1 - mx);
      float e2 = has2 ? expf(v2 - mx) : 0.f;
      float sm = e1 + e2;
#pragma unroll
      for (int off = 32; off > 0; off >>= 1) sm += __shfl_xor(sm, off);
      float rd = 1.f / sm;
      float p1 = e1 * rd, p2 = e2 * rd;
      Psh[c0 * PS + p] = p1;
      if (has2) Psh[(c0 + 64) * PS + p] = p2;
      if (c0 == yb) Pyb[p] = p1;
      if (c0 + 64 == yb) Pyb[p] = p2;
    }
  }
  __syncthreads();  // (3) Psh, Pyb ready; scratch free for reuse

  // ---------------- Phase D: dens; wave (Q, ch): 50-c loop ----------------
  const int Q = g & 3, ch = g >> 2;
  float ap0 = 0.f, ap1 = 0.f, ap2 = 0.f, ap3 = 0.f;
  float an0 = 0.f, an1 = 0.f, an2 = 0.f, an3 = 0.f;
  {
    const float4* P4 = (const float4*)Psh;  // row stride 5 float4
    const int cbeg = ch * 50;
#pragma unroll 5
    for (int ci = 0; ci < 50; ++ci) {
      int c = cbeg + ci;
      float2 pe = epen[c * MH + lane];
      float4 pv = P4[c * 5 + Q];  // broadcast: P[c][Q*4..Q*4+3]
      ap0 = fmaf(pv.x, pe.x, ap0); an0 = fmaf(pv.x, pe.y, an0);
      ap1 = fmaf(pv.y, pe.x, ap1); an1 = fmaf(pv.y, pe.y, an1);
      ap2 = fmaf(pv.z, pe.x, ap2); an2 = fmaf(pv.z, pe.y, an2);
      ap3 = fmaf(pv.w, pe.x, ap3); an3 = fmaf(pv.w, pe.y, an3);
    }
  }

  // ---------------- Phase E: combine c-halves + epilogue ----------------
  float2* exch = (float2*)scratch;  // 16 p * 64 lanes float2 = 8 KB
  if (ch == 1) {
    exch[(Q * 4 + 0) * 64 + lane] = make_float2(ap0, an0);
    exch[(Q * 4 + 1) * 64 + lane] = make_float2(ap1, an1);
    exch[(Q * 4 + 2) * 64 + lane] = make_float2(ap2, an2);
    exch[(Q * 4 + 3) * 64 + lane] = make_float2(ap3, an3);
  }
  __syncthreads();  // (4) partner partials visible
  if (ch == 0) {
    float2 epy = epen[yb * MH + lane];  // (ep[yb][m], en[yb][m])
    float eta_v = esh_eta[lane];
    float ome = 1.f - eta_v;
    int mfull = mh * MH + lane;
    int qz = mfull >> 5, i4z = (mfull >> 2) & 7, jz = mfull & 3;
    int zoff = qz * 32 + ((i4z ^ qz) << 2) + jz;
    float ap[4] = {ap0, ap1, ap2, ap3};
    float an[4] = {an0, an1, an2, an3};
    float o = 0.f;
#pragma unroll
    for (int k = 0; k < 4; ++k) {
      int p = Q * 4 + k;
      float2 other = exch[p * 64 + lane];
      float denp = ap[k] + other.x;
      float denn = an[k] + other.y;
      float z = zsh[p * 128 + zoff];
      float pyb = Pyb[p];
      float contrib;
      if (z > 0.f) {
        contrib = fmaf(pyb, eta_v, (pyb * epy.y / denn) * ome);
      } else {
        contrib = fmaf(pyb * epy.x / denp, eta_v, pyb * ome);
      }
      o += contrib;
    }
    atomicAdd(&out[b * M_ + mh * MH + lane], o);
  }
}

extern "C" void kernel_launch(void* const* d_in, const int* in_sizes, int n_in,
                              void* d_out, int out_size, void* d_ws, size_t ws_size,
                              hipStream_t stream) {
  const float* x = (const float*)d_in[0];
  const int* y = (const int*)d_in[1];
  const float* Z = (const float*)d_in[2];
  const float* alpha0 = (const float*)d_in[3];
  const float* alpha = (const float*)d_in[4];
  const float* beta0 = (const float*)d_in[5];
  const float* beta = (const float*)d_in[6];
  float* out = (float*)d_out;

  hipMemsetAsync(out, 0, (size_t)B_ * M_ * sizeof(float), stream);
  k_main<<<dim3(2, 2, B_), dim3(512), 0, stream>>>(x, y, Z, alpha0, alpha,
                                                   beta0, beta, out);
}

// Round 6
// 17.767 us; speedup vs baseline: 1.8381x; 1.8381x over previous
//
#include <hip/hip_runtime.h>
#include <math.h>

#define S_ 32
#define B_ 128
#define M_ 128
#define F_ 512
#define C_ 100
#define RWZ 136   // f16 row width for Zf/BT (272 B rows: 2-way-free banks, fits K=128 reads)
#define RWE 120   // f16 row width for EPT/ENT/Pt (240 B rows: 2-way-free, fits K=112 reads)

typedef _Float16 f16;
typedef _Float16 f16x2 __attribute__((ext_vector_type(2)));
typedef _Float16 f16x4 __attribute__((ext_vector_type(4)));
typedef _Float16 f16x8 __attribute__((ext_vector_type(8)));
typedef float f32x4 __attribute__((ext_vector_type(4)));

// One block per b. 512 threads = 8 waves.
// B: base[32 p][112 c] = Z(f16)[32][128] x BT(f16)[112][128]^T-style (K=m)
// D: den_pm[32 p][128 m] = P(f16)[32][112] x EPT/ENT[128 m][112 c] (K=c)
__global__ __launch_bounds__(512) void k_main(
    const float* __restrict__ x, const int* __restrict__ y,
    const float* __restrict__ Z, const float* __restrict__ alpha0,
    const float* __restrict__ alpha, const float* __restrict__ beta0,
    const float* __restrict__ beta, float* __restrict__ out) {
  const int b = blockIdx.x;
  const int tid = threadIdx.x;
  const int lane = tid & 63;
  const int w = tid >> 6;   // wave 0..7
  const int l15 = lane & 15;
  const int lg = lane >> 4; // 0..3

  __shared__ f16 Zf[S_ * RWZ];       // [p][m]   8704 B
  __shared__ f16 BT[112 * RWZ];      // [c][m]  30464 B (rows 100..111 zeroed)
  __shared__ f16 EPT[M_ * RWE];      // [m][c]  30720 B  exp(+2*beta)
  __shared__ f16 ENT[M_ * RWE];      // [m][c]  30720 B  exp(-2*beta)
  __shared__ float baseS[S_ * 112];  //         14336 B
  __shared__ f16 Pt[S_ * RWE];       // [p][c]   7680 B
  __shared__ float etaS[M_];
  __shared__ float PybS[S_];

  const int yb = y[b];

  // ---------------- A1: stage Z, beta -> f16 LDS ----------------
  {
    const float4* Z4 = (const float4*)Z;
#pragma unroll
    for (int i4 = tid; i4 < 1024; i4 += 512) {
      int p = i4 >> 5;
      int mj = (i4 & 31) * 4;
      float4 v = Z4[((size_t)p * B_ + b) * 32 + (i4 & 31)];
      f16x4 h = {(f16)v.x, (f16)v.y, (f16)v.z, (f16)v.w};
      *(f16x4*)&Zf[p * RWZ + mj] = h;
    }
    const float4* be4 = (const float4*)beta;
    for (int i4 = tid; i4 < 3200; i4 += 512) {
      int c = i4 >> 5;
      int mj = (i4 & 31) * 4;
      float4 v = be4[i4];
      f16x4 h = {(f16)v.x, (f16)v.y, (f16)v.z, (f16)v.w};
      *(f16x4*)&BT[c * RWZ + mj] = h;
    }
    for (int i = tid; i < 12 * RWZ; i += 512) BT[100 * RWZ + i] = (f16)0.f;
  }
  __syncthreads();

  // ---------------- A2: exp tables (transpose) + eta ----------------
  {
    for (int i = tid; i < 8192; i += 512) {  // (64 m-pairs) x (128 c-slots)
      int c = i & 127;
      int m2 = (i >> 7) << 1;
      if (c < 112) {
        float ep0 = 0.f, en0 = 0.f, ep1 = 0.f, en1 = 0.f;
        if (c < C_) {
          f16x2 bb = *(const f16x2*)&BT[c * RWZ + m2];
          float b0 = (float)bb[0], b1 = (float)bb[1];
          ep0 = __expf(2.f * b0); en0 = __expf(-2.f * b0);
          ep1 = __expf(2.f * b1); en1 = __expf(-2.f * b1);
        }
        EPT[m2 * RWE + c] = (f16)ep0; EPT[(m2 + 1) * RWE + c] = (f16)ep1;
        ENT[m2 * RWE + c] = (f16)en0; ENT[(m2 + 1) * RWE + c] = (f16)en1;
      }
    }
    // eta: wave w covers m = w*16 + j*4 + (lane>>4); 16 lanes split K=512
    const float4* x4 = (const float4*)x;
    const float4* a4 = (const float4*)alpha;
    float4 xr[8];
#pragma unroll
    for (int r = 0; r < 8; ++r) xr[r] = x4[b * 128 + r * 16 + l15];
#pragma unroll
    for (int j = 0; j < 4; ++j) {
      int m = w * 16 + j * 4 + lg;
      float acc = 0.f;
#pragma unroll
      for (int r = 0; r < 8; ++r) {
        float4 av = a4[(size_t)m * 128 + r * 16 + l15];
        float4 xv = xr[r];
        acc = fmaf(av.x, xv.x, acc); acc = fmaf(av.y, xv.y, acc);
        acc = fmaf(av.z, xv.z, acc); acc = fmaf(av.w, xv.w, acc);
      }
      acc += __shfl_xor(acc, 1);
      acc += __shfl_xor(acc, 2);
      acc += __shfl_xor(acc, 4);
      acc += __shfl_xor(acc, 8);
      if (l15 == 0) {
        float l = alpha0[m] + acc;
        etaS[m] = 1.f / (1.f + __expf(-l));
      }
    }
  }
  __syncthreads();

  // ---------------- B: base = Z x beta^T (MFMA), + beta0 ----------------
  if (w < 7) {  // N-tile = w (c block of 16); waves cover c 0..111
    f32x4 acc0 = {0.f, 0.f, 0.f, 0.f}, acc1 = {0.f, 0.f, 0.f, 0.f};
    const char* ZfB = (const char*)Zf;
    const char* BTB = (const char*)BT;
#pragma unroll
    for (int kc = 0; kc < 4; ++kc) {
      int ko = kc * 64 + lg * 16;
      f16x8 a0 = *(const f16x8*)(ZfB + l15 * (RWZ * 2) + ko);
      f16x8 a1 = *(const f16x8*)(ZfB + (16 + l15) * (RWZ * 2) + ko);
      f16x8 bb = *(const f16x8*)(BTB + (w * 16 + l15) * (RWZ * 2) + ko);
      acc0 = __builtin_amdgcn_mfma_f32_16x16x32_f16(a0, bb, acc0, 0, 0, 0);
      acc1 = __builtin_amdgcn_mfma_f32_16x16x32_f16(a1, bb, acc1, 0, 0, 0);
    }
    int col = w * 16 + l15;
    float b0v = (col < C_) ? beta0[col] : 0.f;
#pragma unroll
    for (int j = 0; j < 4; ++j) {
      baseS[(lg * 4 + j) * 112 + col] = acc0[j] + b0v;
      baseS[(16 + lg * 4 + j) * 112 + col] = acc1[j] + b0v;
    }
  }
  __syncthreads();

  // ---------------- C: softmax rows -> Pt f16, PybS ----------------
  {
#pragma unroll
    for (int k = 0; k < 4; ++k) {
      int p = w * 4 + k;
      float v1 = baseS[p * 112 + lane];                         // c = lane < 100
      float v2 = (lane < 36) ? baseS[p * 112 + 64 + lane] : -1e30f;
      float mx = fmaxf(v1, v2);
#pragma unroll
      for (int off = 32; off > 0; off >>= 1) mx = fmaxf(mx, __shfl_xor(mx, off));
      float e1 = __expf(v1 - mx);
      float e2 = (lane < 36) ? __expf(v2 - mx) : 0.f;
      float sm = e1 + e2;
#pragma unroll
      for (int off = 32; off > 0; off >>= 1) sm += __shfl_xor(sm, off);
      float rd = 1.f / sm;
      Pt[p * RWE + lane] = (f16)(e1 * rd);
      if (lane < 48) Pt[p * RWE + 64 + lane] = (f16)(lane < 36 ? e2 * rd : 0.f);
      if (lane == yb) PybS[p] = e1 * rd;
      if (lane + 64 == yb) PybS[p] = e2 * rd;
    }
  }
  __syncthreads();

  // ---------------- D: den± = P x EPT/ENT (MFMA, K=112) + epilogue ----------------
  {
    f32x4 pAcc0 = {0.f,0.f,0.f,0.f}, pAcc1 = {0.f,0.f,0.f,0.f};
    f32x4 nAcc0 = {0.f,0.f,0.f,0.f}, nAcc1 = {0.f,0.f,0.f,0.f};
    const char* PtB = (const char*)Pt;
    const char* EPB = (const char*)EPT;
    const char* ENB = (const char*)ENT;
#pragma unroll
    for (int kc = 0; kc < 3; ++kc) {
      int ko = kc * 64 + lg * 16;
      f16x8 a0 = *(const f16x8*)(PtB + l15 * (RWE * 2) + ko);
      f16x8 a1 = *(const f16x8*)(PtB + (16 + l15) * (RWE * 2) + ko);
      f16x8 bp = *(const f16x8*)(EPB + (w * 16 + l15) * (RWE * 2) + ko);
      f16x8 bn = *(const f16x8*)(ENB + (w * 16 + l15) * (RWE * 2) + ko);
      pAcc0 = __builtin_amdgcn_mfma_f32_16x16x32_f16(a0, bp, pAcc0, 0, 0, 0);
      pAcc1 = __builtin_amdgcn_mfma_f32_16x16x32_f16(a1, bp, pAcc1, 0, 0, 0);
      nAcc0 = __builtin_amdgcn_mfma_f32_16x16x32_f16(a0, bn, nAcc0, 0, 0, 0);
      nAcc1 = __builtin_amdgcn_mfma_f32_16x16x32_f16(a1, bn, nAcc1, 0, 0, 0);
    }
    {  // K-chunk 3: c 96..111 via legacy 16x16x16 (builtin name has no underscore)
      int ko3 = 192 + lg * 8;
      f16x4 a0 = *(const f16x4*)(PtB + l15 * (RWE * 2) + ko3);
      f16x4 a1 = *(const f16x4*)(PtB + (16 + l15) * (RWE * 2) + ko3);
      f16x4 bp = *(const f16x4*)(EPB + (w * 16 + l15) * (RWE * 2) + ko3);
      f16x4 bn = *(const f16x4*)(ENB + (w * 16 + l15) * (RWE * 2) + ko3);
      pAcc0 = __builtin_amdgcn_mfma_f32_16x16x16f16(a0, bp, pAcc0, 0, 0, 0);
      pAcc1 = __builtin_amdgcn_mfma_f32_16x16x16f16(a1, bp, pAcc1, 0, 0, 0);
      nAcc0 = __builtin_amdgcn_mfma_f32_16x16x16f16(a0, bn, nAcc0, 0, 0, 0);
      nAcc1 = __builtin_amdgcn_mfma_f32_16x16x16f16(a1, bn, nAcc1, 0, 0, 0);
    }
    int m = w * 16 + l15;
    float epy = (float)EPT[m * RWE + yb];
    float eny = (float)ENT[m * RWE + yb];
    float eta_v = etaS[m];
    float ome = 1.f - eta_v;
    float o = 0.f;
#pragma unroll
    for (int j = 0; j < 4; ++j) {
      {
        int p = lg * 4 + j;
        float z = (float)Zf[p * RWZ + m];
        float pyb = PybS[p];
        o += (z > 0.f) ? fmaf(pyb, eta_v, (pyb * eny / nAcc0[j]) * ome)
                       : fmaf(pyb * epy / pAcc0[j], eta_v, pyb * ome);
      }
      {
        int p = 16 + lg * 4 + j;
        float z = (float)Zf[p * RWZ + m];
        float pyb = PybS[p];
        o += (z > 0.f) ? fmaf(pyb, eta_v, (pyb * eny / nAcc1[j]) * ome)
                       : fmaf(pyb * epy / pAcc1[j], eta_v, pyb * ome);
      }
    }
    o += __shfl_xor(o, 16);
    o += __shfl_xor(o, 32);
    if (lane < 16) out[b * M_ + w * 16 + lane] = o;
  }
}

extern "C" void kernel_launch(void* const* d_in, const int* in_sizes, int n_in,
                              void* d_out, int out_size, void* d_ws, size_t ws_size,
                              hipStream_t stream) {
  const float* x = (const float*)d_in[0];
  const int* y = (const int*)d_in[1];
  const float* Z = (const float*)d_in[2];
  const float* alpha0 = (const float*)d_in[3];
  const float* alpha = (const float*)d_in[4];
  const float* beta0 = (const float*)d_in[5];
  const float* beta = (const float*)d_in[6];
  float* out = (float*)d_out;

  k_main<<<dim3(B_), dim3(512), 0, stream>>>(x, y, Z, alpha0, alpha, beta0,
                                             beta, out);
}